// Round 6
// baseline (126.778 us; speedup 1.0000x reference)
//
#include <hip/hip_runtime.h>

#define GRID_NUM 7
#define IMG_SIZE 448.0f
#define LAMBDA_COORD 5.0f
#define LAMBDA_NOOBJ 0.5f
#define NUM_CLASSES 20
#define YOLO_EPS 1e-12f

#define TPB 256
#define WPB 4  // waves per block; each wave owns 64 cells, staged per-wave

__device__ __forceinline__ float iou_pair(float px, float py, float pw, float ph,
                                          float tx, float ty, float tw, float th) {
    const float gs = IMG_SIZE / (float)GRID_NUM;  // 64.0
    float cx1 = px * gs, cy1 = py * gs, w1 = pw * IMG_SIZE, h1 = ph * IMG_SIZE;
    float cx2 = tx * gs, cy2 = ty * gs, w2 = tw * IMG_SIZE, h2 = th * IMG_SIZE;
    float ix = fmaxf(fminf(cx1 + 0.5f * w1, cx2 + 0.5f * w2) -
                     fmaxf(cx1 - 0.5f * w1, cx2 - 0.5f * w2), 0.0f);
    float iy = fmaxf(fminf(cy1 + 0.5f * h1, cy2 + 0.5f * h2) -
                     fmaxf(cy1 - 0.5f * h1, cy2 - 0.5f * h2), 0.0f);
    float inter = ix * iy;
    float uni = w1 * h1 + w2 * h2 - inter;
    return inter / (uni + YOLO_EPS);
}

__device__ __forceinline__ float cell_loss(const float* __restrict__ p,
                                           float cls, float gx, float gy,
                                           float gw, float gh) {
    bool obj = (cls != 0.0f);
    float iou0 = iou_pair(p[0], p[1], p[2], p[3], gx, gy, gw, gh);
    float iou1 = iou_pair(p[5], p[6], p[7], p[8], gx, gy, gw, gh);
    bool c0 = iou0 > iou1;

    float l = 0.0f;
    if (obj) {
        float conf_pre  = c0 ? p[4] : p[9];
        float conf_true = c0 ? iou0 : iou1;
        float dc = conf_pre - conf_true;
        l += dc * dc;
        float xp = c0 ? p[0] : p[5];
        float yp = c0 ? p[1] : p[6];
        float dx = xp - gx, dy = yp - gy;
        l += LAMBDA_COORD * (dx * dx + dy * dy);
        float wp = c0 ? p[2] : p[7];
        float hp = c0 ? p[3] : p[8];
        float sw = sqrtf(wp + YOLO_EPS) - sqrtf(gw + YOLO_EPS);
        float sh = sqrtf(hp + YOLO_EPS) - sqrtf(gh + YOLO_EPS);
        l += LAMBDA_COORD * (sw * sw + sh * sh);
        int ci = (int)cls - 1;
#pragma unroll
        for (int c = 0; c < NUM_CLASSES; ++c) {
            float tt = (c == ci) ? 1.0f : 0.0f;
            float dd = p[10 + c] - tt;
            l += dd * dd;
        }
    } else {
        l += LAMBDA_NOOBJ * (p[4] * p[4] + p[9] * p[9]);
    }
    return l;
}

__global__ void __launch_bounds__(TPB) yolo_main(
        const float* __restrict__ y_pre, const float* __restrict__ y_true,
        float* __restrict__ partial, int* __restrict__ counter,
        float* __restrict__ out, float inv_b) {
    // per-wave staging region: 64 cells * 30 floats = 1920 floats = 7680 B
    __shared__ __align__(16) float sp[WPB][1920];
    __shared__ float wsum[WPB];
    __shared__ int isLast;

    const int t = threadIdx.x;
    const int lane = t & 63;
    const int w = t >> 6;
    const int nblocks = gridDim.x;
    const size_t waveCell = (size_t)blockIdx.x * TPB + (size_t)w * 64;

    // ---- coalesced global->LDS stage (per-wave, linear, no barrier needed) ----
    const float4* gsrc = reinterpret_cast<const float4*>(y_pre + waveCell * 30);
    float* lbase = sp[w];
#pragma unroll
    for (int i = 0; i < 7; ++i) {
        __builtin_amdgcn_global_load_lds(
            (const __attribute__((address_space(1))) void*)(gsrc + i * 64 + lane),
            (__attribute__((address_space(3))) void*)(lbase + i * 256),
            16, 0, 0);
    }
    if (lane < 32) {
        __builtin_amdgcn_global_load_lds(
            (const __attribute__((address_space(1))) void*)(gsrc + 448 + lane),
            (__attribute__((address_space(3))) void*)(lbase + 1792),
            16, 0, 0);
    }

    // y_true direct (issued before the wait so it overlaps staging)
    const size_t cell = waveCell + lane;
    const float* tbase = y_true + cell * 8;
    float4 t0 = *reinterpret_cast<const float4*>(tbase);  // cls, x, y, w
    float gh = tbase[4];

    asm volatile("s_waitcnt vmcnt(0)" ::: "memory");

    // ---- LDS -> registers: 15x ds_read_b64 at stride-30 words ----
    float p[30];
    const float2* pl = reinterpret_cast<const float2*>(lbase + lane * 30);
#pragma unroll
    for (int i = 0; i < 15; ++i) {
        float2 v = pl[i];
        p[2 * i]     = v.x;
        p[2 * i + 1] = v.y;
    }

    float acc = cell_loss(p, t0.x, t0.y, t0.z, t0.w, gh);

    // wave-64 reduce -> cross-wave LDS reduce
#pragma unroll
    for (int off = 32; off > 0; off >>= 1)
        acc += __shfl_down(acc, off, 64);

    if (lane == 0) wsum[w] = acc;
    __syncthreads();

    if (t == 0) {
        float s = wsum[0] + wsum[1] + wsum[2] + wsum[3];
        // agent-scope store: visible at device coherence point (cross-XCD safe)
        __hip_atomic_store(&partial[blockIdx.x], s, __ATOMIC_RELAXED,
                           __HIP_MEMORY_SCOPE_AGENT);
        int old = __hip_atomic_fetch_add(counter, 1, __ATOMIC_ACQ_REL,
                                         __HIP_MEMORY_SCOPE_AGENT);
        isLast = (old == nblocks - 1) ? 1 : 0;
    }
    __syncthreads();

    // ---- last arriving block reduces all partials and writes the output ----
    if (isLast) {
        float s = 0.0f;
        for (int i = t; i < nblocks; i += TPB)
            s += __hip_atomic_load(&partial[i], __ATOMIC_RELAXED,
                                   __HIP_MEMORY_SCOPE_AGENT);
#pragma unroll
        for (int off = 32; off > 0; off >>= 1)
            s += __shfl_down(s, off, 64);
        if (lane == 0) wsum[w] = s;
        __syncthreads();
        if (t == 0)
            out[0] = (wsum[0] + wsum[1] + wsum[2] + wsum[3]) * inv_b;
    }
}

extern "C" void kernel_launch(void* const* d_in, const int* in_sizes, int n_in,
                              void* d_out, int out_size, void* d_ws, size_t ws_size,
                              hipStream_t stream) {
    const float* y_pre  = (const float*)d_in[0];
    const float* y_true = (const float*)d_in[1];
    float* out = (float*)d_out;
    float* partial = (float*)d_ws;                 // [grid] floats
    int* counter = (int*)((char*)d_ws + 65536);    // one int, well past partials

    const int B = in_sizes[0] / (GRID_NUM * GRID_NUM * 30);  // 16384
    const int ncells = B * GRID_NUM * GRID_NUM;              // 802816 (divisible by 256)
    const float inv_b = 1.0f / (float)B;
    const int grid = ncells / TPB;                           // 3136

    hipMemsetAsync(counter, 0, sizeof(int), stream);
    yolo_main<<<grid, TPB, 0, stream>>>(y_pre, y_true, partial, counter, out, inv_b);
}

// Round 8
// 25.638 us; speedup vs baseline: 4.9450x; 4.9450x over previous
//
#include <hip/hip_runtime.h>

#define GRID_NUM 7
#define IMG_SIZE 448.0f
#define LAMBDA_COORD 5.0f
#define LAMBDA_NOOBJ 0.5f
#define NUM_CLASSES 20
#define YOLO_EPS 1e-12f

#define TPB 256
#define WPB 4  // waves per block; each wave owns 64 cells, staged per-wave

__device__ __forceinline__ float iou_pair(float px, float py, float pw, float ph,
                                          float tx, float ty, float tw, float th) {
    const float gs = IMG_SIZE / (float)GRID_NUM;  // 64.0
    float cx1 = px * gs, cy1 = py * gs, w1 = pw * IMG_SIZE, h1 = ph * IMG_SIZE;
    float cx2 = tx * gs, cy2 = ty * gs, w2 = tw * IMG_SIZE, h2 = th * IMG_SIZE;
    float ix = fmaxf(fminf(cx1 + 0.5f * w1, cx2 + 0.5f * w2) -
                     fmaxf(cx1 - 0.5f * w1, cx2 - 0.5f * w2), 0.0f);
    float iy = fmaxf(fminf(cy1 + 0.5f * h1, cy2 + 0.5f * h2) -
                     fmaxf(cy1 - 0.5f * h1, cy2 - 0.5f * h2), 0.0f);
    float inter = ix * iy;
    float uni = w1 * h1 + w2 * h2 - inter;
    return inter / (uni + YOLO_EPS);
}

__device__ __forceinline__ float cell_loss(const float* __restrict__ p,
                                           float cls, float gx, float gy,
                                           float gw, float gh) {
    bool obj = (cls != 0.0f);
    float iou0 = iou_pair(p[0], p[1], p[2], p[3], gx, gy, gw, gh);
    float iou1 = iou_pair(p[5], p[6], p[7], p[8], gx, gy, gw, gh);
    bool c0 = iou0 > iou1;

    float l = 0.0f;
    if (obj) {
        float conf_pre  = c0 ? p[4] : p[9];
        float conf_true = c0 ? iou0 : iou1;
        float dc = conf_pre - conf_true;
        l += dc * dc;
        float xp = c0 ? p[0] : p[5];
        float yp = c0 ? p[1] : p[6];
        float dx = xp - gx, dy = yp - gy;
        l += LAMBDA_COORD * (dx * dx + dy * dy);
        float wp = c0 ? p[2] : p[7];
        float hp = c0 ? p[3] : p[8];
        float sw = sqrtf(wp + YOLO_EPS) - sqrtf(gw + YOLO_EPS);
        float sh = sqrtf(hp + YOLO_EPS) - sqrtf(gh + YOLO_EPS);
        l += LAMBDA_COORD * (sw * sw + sh * sh);
        int ci = (int)cls - 1;
#pragma unroll
        for (int c = 0; c < NUM_CLASSES; ++c) {
            float tt = (c == ci) ? 1.0f : 0.0f;
            float dd = p[10 + c] - tt;
            l += dd * dd;
        }
    } else {
        l += LAMBDA_NOOBJ * (p[4] * p[4] + p[9] * p[9]);
    }
    return l;
}

__global__ void __launch_bounds__(TPB) yolo_main(
        const float* __restrict__ y_pre, const float* __restrict__ y_true,
        float* __restrict__ partial) {
    // per-wave staging region: 64 cells * 30 floats = 1920 floats = 7680 B
    __shared__ __align__(16) float sp[WPB][1920];
    __shared__ float wsum[WPB];

    const int t = threadIdx.x;
    const int lane = t & 63;
    const int w = t >> 6;
    const size_t waveCell = (size_t)blockIdx.x * TPB + (size_t)w * 64;

    // ---- coalesced global->LDS stage of y_pre (per-wave, linear, no barrier) ----
    const float4* gsrc = reinterpret_cast<const float4*>(y_pre + waveCell * 30);
    float* lbase = sp[w];
#pragma unroll
    for (int i = 0; i < 7; ++i) {
        __builtin_amdgcn_global_load_lds(
            (const __attribute__((address_space(1))) void*)(gsrc + i * 64 + lane),
            (__attribute__((address_space(3))) void*)(lbase + i * 256),
            16, 0, 0);
    }
    if (lane < 32) {
        __builtin_amdgcn_global_load_lds(
            (const __attribute__((address_space(1))) void*)(gsrc + 448 + lane),
            (__attribute__((address_space(3))) void*)(lbase + 1792),
            16, 0, 0);
    }

    // ---- y_true: two fully-coalesced float4 rounds (1024B contiguous each) ----
    // cell c first-half = float4 #2c ([cls,x,y,w]); h = float4 #(2c+1).x
    const float4* tq = reinterpret_cast<const float4*>(y_true + waveCell * 8);
    float4 r0 = tq[lane];        // float4 idx 0..63   -> cells 0..31
    float4 r1 = tq[64 + lane];   // float4 idx 64..127 -> cells 32..63

    asm volatile("s_waitcnt vmcnt(0)" ::: "memory");

    // Redistribute to the owning lane. ALL shuffles run under uniform control
    // flow (every lane executes both); per-lane select happens on registers
    // AFTER the shuffle (cndmask), never around it. (R7 bug: divergent shfl.)
    const int sl  = (2 * lane) & 63;
    const int slh = (2 * lane + 1) & 63;
    const bool lo = (lane < 32);
    float c0v = __shfl(r0.x, sl, 64),  c1v = __shfl(r1.x, sl, 64);
    float x0v = __shfl(r0.y, sl, 64),  x1v = __shfl(r1.y, sl, 64);
    float y0v = __shfl(r0.z, sl, 64),  y1v = __shfl(r1.z, sl, 64);
    float w0v = __shfl(r0.w, sl, 64),  w1v = __shfl(r1.w, sl, 64);
    float h0v = __shfl(r0.x, slh, 64), h1v = __shfl(r1.x, slh, 64);
    float cls = lo ? c0v : c1v;
    float gx  = lo ? x0v : x1v;
    float gy  = lo ? y0v : y1v;
    float gw  = lo ? w0v : w1v;
    float gh  = lo ? h0v : h1v;

    // ---- LDS -> registers: 15x ds_read_b64 at stride-30 words ----
    float p[30];
    const float2* pl = reinterpret_cast<const float2*>(lbase + lane * 30);
#pragma unroll
    for (int i = 0; i < 15; ++i) {
        float2 v = pl[i];
        p[2 * i]     = v.x;
        p[2 * i + 1] = v.y;
    }

    float acc = cell_loss(p, cls, gx, gy, gw, gh);

    // wave-64 reduce -> cross-wave LDS reduce -> ONE partial per block
#pragma unroll
    for (int off = 32; off > 0; off >>= 1)
        acc += __shfl_down(acc, off, 64);

    if (lane == 0) wsum[w] = acc;
    __syncthreads();
    if (t == 0)
        partial[blockIdx.x] = wsum[0] + wsum[1] + wsum[2] + wsum[3];
}

__global__ void __launch_bounds__(256) yolo_reduce(
        const float* __restrict__ partial, float* __restrict__ out,
        int n4, float inv_b) {
    // n4 = 784 float4s (3136 floats); 784 = 3*256 + 16.
    // Issue all 4 loads independently before any use -> one latency round.
    const float4* p4 = reinterpret_cast<const float4*>(partial);
    const int i = threadIdx.x;
    float4 a = p4[i];
    float4 b = p4[i + 256];
    float4 c = p4[i + 512];
    float4 d = (i + 768 < n4) ? p4[i + 768] : make_float4(0.f, 0.f, 0.f, 0.f);

    float s = (a.x + a.y + a.z + a.w) + (b.x + b.y + b.z + b.w) +
              (c.x + c.y + c.z + c.w) + (d.x + d.y + d.z + d.w);

#pragma unroll
    for (int off = 32; off > 0; off >>= 1)
        s += __shfl_down(s, off, 64);

    __shared__ float wsum[4];
    int lane = threadIdx.x & 63, wid = threadIdx.x >> 6;
    if (lane == 0) wsum[wid] = s;
    __syncthreads();
    if (threadIdx.x == 0)
        out[0] = (wsum[0] + wsum[1] + wsum[2] + wsum[3]) * inv_b;
}

extern "C" void kernel_launch(void* const* d_in, const int* in_sizes, int n_in,
                              void* d_out, int out_size, void* d_ws, size_t ws_size,
                              hipStream_t stream) {
    const float* y_pre  = (const float*)d_in[0];
    const float* y_true = (const float*)d_in[1];
    float* out = (float*)d_out;
    float* partial = (float*)d_ws;

    const int B = in_sizes[0] / (GRID_NUM * GRID_NUM * 30);  // 16384
    const int ncells = B * GRID_NUM * GRID_NUM;              // 802816 (divisible by 256)
    const float inv_b = 1.0f / (float)B;

    const int grid = ncells / TPB;                           // 3136
    yolo_main<<<grid, TPB, 0, stream>>>(y_pre, y_true, partial);
    yolo_reduce<<<1, 256, 0, stream>>>(partial, out, grid / 4, inv_b);
}